// Round 3
// baseline (672.972 us; speedup 1.0000x reference)
//
#include <hip/hip_runtime.h>
#include <hip/hip_bf16.h>

#define EMBED 768
#define NHEADS 12
#define HDIM 64
#define WIN 64
#define BATCH 2
#define SEQ 2048
#define MROWS (BATCH*SEQ)      // 4096
#define NBH (BATCH*NHEADS)     // 24
#define PSTRIDE 132            // probs row stride (floats), 132*4=528 B (16B aligned)

typedef __attribute__((ext_vector_type(8))) short short8;
typedef __attribute__((ext_vector_type(4))) float f32x4;

__device__ __forceinline__ float bf2f(unsigned short u) {
    union { unsigned int i; float f; } z;
    z.i = ((unsigned int)u) << 16;
    return z.f;
}
__device__ __forceinline__ unsigned short f2bf(float f) {
    __hip_bfloat16 h = __float2bfloat16(f);
    return *reinterpret_cast<unsigned short*>(&h);
}

// ---------------- fp32 -> bf16 conversion ----------------
__global__ void cvt_f32_bf16(const float* __restrict__ src,
                             unsigned short* __restrict__ dst, int n4) {
    int i = blockIdx.x * blockDim.x + threadIdx.x;
    if (i < n4) {
        float4 v = reinterpret_cast<const float4*>(src)[i];
        ushort4 o;
        o.x = f2bf(v.x); o.y = f2bf(v.y); o.z = f2bf(v.z); o.w = f2bf(v.w);
        reinterpret_cast<ushort4*>(dst)[i] = o;
    }
}

// ---------------- bf16 NT GEMM: C[M,N] = A[M,K] * B[N,K]^T + bias ----------------
struct GArgs {
    const unsigned short* A[3];
    const unsigned short* Bm[3];
    const float* bias[3];
    void* C[3];
};

template<int F32OUT>
__global__ __launch_bounds__(256) void gemm_nt(GArgs ga, int M, int N, int K) {
    const int z = blockIdx.z;
    const unsigned short* __restrict__ A  = ga.A[z];
    const unsigned short* __restrict__ Bm = ga.Bm[z];
    const float* __restrict__ bias = ga.bias[z];

    const int bm = blockIdx.y * 128;
    const int bn = blockIdx.x * 128;

    __shared__ unsigned short As[128][40];
    __shared__ unsigned short Bs[128][40];

    const int tid = threadIdx.x;
    const int lane = tid & 63;
    const int wid = tid >> 6;
    const int wm = wid >> 1, wn = wid & 1;

    f32x4 acc[4][4] = {};

    const int fr = lane & 15;
    const int krow = (lane >> 4) * 8;

    for (int k0 = 0; k0 < K; k0 += 32) {
#pragma unroll
        for (int it = 0; it < 2; ++it) {
            int idx = tid + it * 256;     // chunk of 8 bf16
            int r = idx >> 2;
            int c = (idx & 3) * 8;
            int4 av = *reinterpret_cast<const int4*>(A + (size_t)(bm + r) * K + k0 + c);
            *reinterpret_cast<int4*>(&As[r][c]) = av;
            int4 bv = *reinterpret_cast<const int4*>(Bm + (size_t)(bn + r) * K + k0 + c);
            *reinterpret_cast<int4*>(&Bs[r][c]) = bv;
        }
        __syncthreads();

        short8 af[4], bfv[4];
#pragma unroll
        for (int mf = 0; mf < 4; ++mf)
            af[mf] = *reinterpret_cast<const short8*>(&As[wm * 64 + mf * 16 + fr][krow]);
#pragma unroll
        for (int nf = 0; nf < 4; ++nf)
            bfv[nf] = *reinterpret_cast<const short8*>(&Bs[wn * 64 + nf * 16 + fr][krow]);
#pragma unroll
        for (int mf = 0; mf < 4; ++mf)
#pragma unroll
            for (int nf = 0; nf < 4; ++nf)
                acc[mf][nf] = __builtin_amdgcn_mfma_f32_16x16x32_bf16(
                    af[mf], bfv[nf], acc[mf][nf], 0, 0, 0);
        __syncthreads();
    }

    const int fq = lane >> 4;
#pragma unroll
    for (int mf = 0; mf < 4; ++mf)
#pragma unroll
        for (int nf = 0; nf < 4; ++nf) {
            int col = bn + wn * 64 + nf * 16 + fr;
            float bv = bias[col];
#pragma unroll
            for (int r = 0; r < 4; ++r) {
                int row = bm + wm * 64 + mf * 16 + fq * 4 + r;
                float v = acc[mf][nf][r] + bv;
                if (F32OUT)
                    reinterpret_cast<float*>(ga.C[z])[(size_t)row * N + col] = v;
                else
                    reinterpret_cast<unsigned short*>(ga.C[z])[(size_t)row * N + col] = f2bf(v);
            }
        }
}

// ---------------- sum of V over keys, per (b,h,d) ----------------
__global__ void sumv_kernel(const unsigned short* __restrict__ Vb,
                            float* __restrict__ sumV) {
    __shared__ float r[4][HDIM];
    int bh = blockIdx.x;
    int b = bh / NHEADS, h = bh % NHEADS;
    int d = threadIdx.x & 63;
    int kc = threadIdx.x >> 6;
    float acc = 0.f;
    for (int j = kc; j < SEQ; j += 4)
        acc += bf2f(Vb[((size_t)(b * SEQ + j)) * EMBED + h * HDIM + d]);
    r[kc][d] = acc;
    __syncthreads();
    if (threadIdx.x < HDIM)
        sumV[bh * HDIM + threadIdx.x] =
            r[0][threadIdx.x] + r[1][threadIdx.x] + r[2][threadIdx.x] + r[3][threadIdx.x];
}

// ---------------- band softmax + PV (compact outputs only) ----------------
__global__ __launch_bounds__(256) void attn_band_kernel(
    const unsigned short* __restrict__ Q,
    const unsigned short* __restrict__ Kb,
    const unsigned short* __restrict__ Vb,
    const unsigned char* __restrict__ kpm,
    const float* __restrict__ sumV,
    float* __restrict__ probs,      // [BATCH*NHEADS*SEQ][PSTRIDE], p+1e-6
    unsigned short* __restrict__ ctx) {
    const int bid = blockIdx.x;
    const int qi = bid & (SEQ - 1);
    const int bh = bid >> 11;
    const int h = bh % NHEADS;
    const int b = bh / NHEADS;

    const int qlo = max(qi - WIN, 0);
    const int qhi = min(qi + WIN, SEQ - 1);
    const int nk = qhi - qlo + 1;   // <= 129

    __shared__ float q_l[HDIM];
    __shared__ float p_l[2 * WIN + 8];
    __shared__ float red[8];
    __shared__ float ctxred[4][HDIM];

    const int tid = threadIdx.x;
    const int lane = tid & 63;
    const int wid = tid >> 6;

    if (tid < HDIM)
        q_l[tid] = bf2f(Q[((size_t)(b * SEQ + qi)) * EMBED + h * HDIM + tid]);
    __syncthreads();

    // ---- scores for band keys (two independent accumulator chains for ILP) ----
    float s = -1e30f;
    if (tid < nk) {
        const int j = qlo + tid;
        const int4* kr = reinterpret_cast<const int4*>(
            Kb + ((size_t)(b * SEQ + j)) * EMBED + h * HDIM);
        int4 pk[8];
#pragma unroll
        for (int c = 0; c < 8; ++c) pk[c] = kr[c];    // issue all loads first
        float acc0 = 0.f, acc1 = 0.f;
#pragma unroll
        for (int c = 0; c < 8; ++c) {
            const unsigned short* u = reinterpret_cast<const unsigned short*>(&pk[c]);
#pragma unroll
            for (int e = 0; e < 8; e += 2) {
                acc0 += q_l[c * 8 + e] * bf2f(u[e]);
                acc1 += q_l[c * 8 + e + 1] * bf2f(u[e + 1]);
            }
        }
        s = (acc0 + acc1) * 0.125f;
        if (kpm[b * SEQ + j]) s = -10000.f;
    }

    // ---- block max ----
    float m = s;
#pragma unroll
    for (int off = 32; off; off >>= 1) m = fmaxf(m, __shfl_xor(m, off));
    if (lane == 0) red[wid] = m;
    __syncthreads();
    m = fmaxf(fmaxf(red[0], red[1]), fmaxf(red[2], red[3]));

    // ---- exp & sum ----
    float p = (tid < nk) ? __expf(s - m) : 0.f;
    float dsum = p;
#pragma unroll
    for (int off = 32; off; off >>= 1) dsum += __shfl_xor(dsum, off);
    __syncthreads();
    if (lane == 0) red[wid] = dsum;
    __syncthreads();
    dsum = red[0] + red[1] + red[2] + red[3];
    p = p / dsum;
    if (tid < nk) p_l[tid] = p;

    // ---- compact probs row (+1e-6 folded in) ----
    if (tid < nk)
        probs[(size_t)bid * PSTRIDE + tid] = p + 1e-6f;
    __syncthreads();

    // ---- PV: ctx = sum_band p*V + 1e-6 * sumV ----
    {
        const int d = tid & 63;
        const int kc = tid >> 6;
        float acc = 0.f;
        for (int j = kc; j < nk; j += 4)
            acc += p_l[j] * bf2f(Vb[((size_t)(b * SEQ + qlo + j)) * EMBED + h * HDIM + d]);
        ctxred[kc][d] = acc;
        __syncthreads();
        if (tid < HDIM) {
            float c = ctxred[0][tid] + ctxred[1][tid] + ctxred[2][tid] + ctxred[3][tid]
                    + 1e-6f * sumV[bh * HDIM + tid];
            ctx[((size_t)(b * SEQ + qi)) * EMBED + tid + h * HDIM] = f2bf(c);
        }
    }
}

// ---------------- streaming fill of the full attn tensor ----------------
__global__ __launch_bounds__(256) void fill_kernel(
    const float* __restrict__ probs,
    float* __restrict__ attn_out) {
    const int row = blockIdx.x;             // bh*SEQ + qi
    const int qi = row & (SEQ - 1);
    const int qlo = max(qi - WIN, 0);
    const int qhi = min(qi + WIN, SEQ - 1);
    const float* __restrict__ prow = probs + (size_t)row * PSTRIDE;
    float* __restrict__ orow = attn_out + (size_t)row * SEQ;

    const int c0 = threadIdx.x * 8;
    f32x4 v0 = {1e-6f, 1e-6f, 1e-6f, 1e-6f};
    f32x4 v1 = v0;
    if (c0 + 7 >= qlo && c0 <= qhi) {       // touches the band
        float v[8];
#pragma unroll
        for (int e = 0; e < 8; ++e) {
            int c = c0 + e;
            v[e] = (c >= qlo && c <= qhi) ? prow[c - qlo] : 1e-6f;
        }
        v0 = f32x4{v[0], v[1], v[2], v[3]};
        v1 = f32x4{v[4], v[5], v[6], v[7]};
    }
    __builtin_nontemporal_store(v0, reinterpret_cast<f32x4*>(orow + c0));
    __builtin_nontemporal_store(v1, reinterpret_cast<f32x4*>(orow + c0 + 4));
}

// ---------------- host ----------------
extern "C" void kernel_launch(void* const* d_in, const int* in_sizes, int n_in,
                              void* d_out, int out_size, void* d_ws, size_t ws_size,
                              hipStream_t stream) {
    const float* q_in = (const float*)d_in[0];
    const float* k_in = (const float*)d_in[1];
    const float* v_in = (const float*)d_in[2];
    const unsigned char* kpm = (const unsigned char*)d_in[3];
    const float* Wq = (const float*)d_in[4];
    const float* bq = (const float*)d_in[5];
    const float* Wk = (const float*)d_in[6];
    const float* bk = (const float*)d_in[7];
    const float* Wv = (const float*)d_in[8];
    const float* bv = (const float*)d_in[9];
    const float* Wo = (const float*)d_in[10];
    const float* bo = (const float*)d_in[11];

    char* ws = (char*)d_ws;
    size_t off = 0;
    auto alloc = [&](size_t bytes) {
        void* p = ws + off;
        off += (bytes + 255) & ~255ULL;
        return p;
    };
    const size_t XB = (size_t)MROWS * EMBED * 2;  // bf16 [4096,768]
    const size_t WB = (size_t)EMBED * EMBED * 2;  // bf16 [768,768]
    unsigned short* xq = (unsigned short*)alloc(XB);
    unsigned short* xk = (unsigned short*)alloc(XB);
    unsigned short* xv = (unsigned short*)alloc(XB);
    unsigned short* wqb = (unsigned short*)alloc(WB);
    unsigned short* wkb = (unsigned short*)alloc(WB);
    unsigned short* wvb = (unsigned short*)alloc(WB);
    unsigned short* wob = (unsigned short*)alloc(WB);
    unsigned short* Qb = (unsigned short*)alloc(XB);
    unsigned short* Kb = (unsigned short*)alloc(XB);
    unsigned short* Vb = (unsigned short*)alloc(XB);
    unsigned short* ctx = (unsigned short*)alloc(XB);
    float* sumV = (float*)alloc((size_t)NBH * HDIM * 4);
    float* probs = (float*)alloc((size_t)NBH * SEQ * PSTRIDE * 4);  // ~26 MB

    float* out0 = (float*)d_out;
    float* attn_out = out0 + (size_t)MROWS * EMBED;  // [B,H,S,S]

    // convert inputs + weights to bf16
    {
        int n4x = MROWS * EMBED / 4;
        int n4w = EMBED * EMBED / 4;
        dim3 blk(256);
        cvt_f32_bf16<<<dim3((n4x + 255) / 256), blk, 0, stream>>>(q_in, xq, n4x);
        cvt_f32_bf16<<<dim3((n4x + 255) / 256), blk, 0, stream>>>(k_in, xk, n4x);
        cvt_f32_bf16<<<dim3((n4x + 255) / 256), blk, 0, stream>>>(v_in, xv, n4x);
        cvt_f32_bf16<<<dim3((n4w + 255) / 256), blk, 0, stream>>>(Wq, wqb, n4w);
        cvt_f32_bf16<<<dim3((n4w + 255) / 256), blk, 0, stream>>>(Wk, wkb, n4w);
        cvt_f32_bf16<<<dim3((n4w + 255) / 256), blk, 0, stream>>>(Wv, wvb, n4w);
        cvt_f32_bf16<<<dim3((n4w + 255) / 256), blk, 0, stream>>>(Wo, wob, n4w);
    }

    // QKV projections (batched, z selects q/k/v)
    {
        GArgs ga;
        ga.A[0] = xq;  ga.A[1] = xk;  ga.A[2] = xv;
        ga.Bm[0] = wqb; ga.Bm[1] = wkb; ga.Bm[2] = wvb;
        ga.bias[0] = bq; ga.bias[1] = bk; ga.bias[2] = bv;
        ga.C[0] = Qb; ga.C[1] = Kb; ga.C[2] = Vb;
        gemm_nt<0><<<dim3(EMBED / 128, MROWS / 128, 3), dim3(256), 0, stream>>>(
            ga, MROWS, EMBED, EMBED);
    }

    sumv_kernel<<<dim3(NBH), dim3(256), 0, stream>>>(Vb, sumV);

    attn_band_kernel<<<dim3(NBH * SEQ), dim3(256), 0, stream>>>(
        Qb, Kb, Vb, kpm, sumV, probs, ctx);

    fill_kernel<<<dim3(NBH * SEQ), dim3(256), 0, stream>>>(probs, attn_out);

    // output projection -> fp32 out
    {
        GArgs ga;
        ga.A[0] = ctx;  ga.A[1] = ctx;  ga.A[2] = ctx;
        ga.Bm[0] = wob; ga.Bm[1] = wob; ga.Bm[2] = wob;
        ga.bias[0] = bo; ga.bias[1] = bo; ga.bias[2] = bo;
        ga.C[0] = out0; ga.C[1] = out0; ga.C[2] = out0;
        gemm_nt<1><<<dim3(EMBED / 128, MROWS / 128, 1), dim3(256), 0, stream>>>(
            ga, MROWS, EMBED, EMBED);
    }
}

// Round 4
// 398.673 us; speedup vs baseline: 1.6880x; 1.6880x over previous
//
#include <hip/hip_runtime.h>
#include <hip/hip_bf16.h>

#define EMBED 768
#define NHEADS 12
#define HDIM 64
#define WIN 64
#define BATCH 2
#define SEQ 2048
#define MROWS (BATCH*SEQ)      // 4096
#define NBH (BATCH*NHEADS)     // 24

typedef __attribute__((ext_vector_type(8))) short short8;
typedef __attribute__((ext_vector_type(4))) float f32x4;

__device__ __forceinline__ float bf2f(unsigned short u) {
    union { unsigned int i; float f; } z;
    z.i = ((unsigned int)u) << 16;
    return z.f;
}
__device__ __forceinline__ unsigned short f2bf(float f) {
    __hip_bfloat16 h = __float2bfloat16(f);
    return *reinterpret_cast<unsigned short*>(&h);
}

// ---------------- fused fp32 -> bf16 conversion (7 segments, 1 launch) ----------------
struct CvtArgs {
    const float* src[7];
    unsigned short* dst[7];
    int n4[7];
    int bstart[8];   // block range per segment
};

__global__ __launch_bounds__(256) void cvt_all(CvtArgs ca) {
    int bid = blockIdx.x;
    int seg = 0;
#pragma unroll
    for (int s = 0; s < 6; ++s)
        if (bid >= ca.bstart[s + 1]) seg = s + 1;
    int i = (bid - ca.bstart[seg]) * 256 + threadIdx.x;
    if (i < ca.n4[seg]) {
        float4 v = reinterpret_cast<const float4*>(ca.src[seg])[i];
        ushort4 o;
        o.x = f2bf(v.x); o.y = f2bf(v.y); o.z = f2bf(v.z); o.w = f2bf(v.w);
        reinterpret_cast<ushort4*>(ca.dst[seg])[i] = o;
    }
}

// ---------------- bf16 NT GEMM: C[M,N] = A[M,K] * B[N,K]^T + bias ----------------
struct GArgs {
    const unsigned short* A[3];
    const unsigned short* Bm[3];
    const float* bias[3];
    void* C[3];
};

template<int F32OUT>
__global__ __launch_bounds__(256) void gemm_nt(GArgs ga, int M, int N, int K) {
    const int z = blockIdx.z;
    const unsigned short* __restrict__ A  = ga.A[z];
    const unsigned short* __restrict__ Bm = ga.Bm[z];
    const float* __restrict__ bias = ga.bias[z];

    const int bm = blockIdx.y * 128;
    const int bn = blockIdx.x * 128;

    __shared__ unsigned short As[128][40];
    __shared__ unsigned short Bs[128][40];

    const int tid = threadIdx.x;
    const int lane = tid & 63;
    const int wid = tid >> 6;
    const int wm = wid >> 1, wn = wid & 1;

    f32x4 acc[4][4] = {};

    const int fr = lane & 15;
    const int krow = (lane >> 4) * 8;

    for (int k0 = 0; k0 < K; k0 += 32) {
#pragma unroll
        for (int it = 0; it < 2; ++it) {
            int idx = tid + it * 256;     // chunk of 8 bf16
            int r = idx >> 2;
            int c = (idx & 3) * 8;
            int4 av = *reinterpret_cast<const int4*>(A + (size_t)(bm + r) * K + k0 + c);
            *reinterpret_cast<int4*>(&As[r][c]) = av;
            int4 bv = *reinterpret_cast<const int4*>(Bm + (size_t)(bn + r) * K + k0 + c);
            *reinterpret_cast<int4*>(&Bs[r][c]) = bv;
        }
        __syncthreads();

        short8 af[4], bfv[4];
#pragma unroll
        for (int mf = 0; mf < 4; ++mf)
            af[mf] = *reinterpret_cast<const short8*>(&As[wm * 64 + mf * 16 + fr][krow]);
#pragma unroll
        for (int nf = 0; nf < 4; ++nf)
            bfv[nf] = *reinterpret_cast<const short8*>(&Bs[wn * 64 + nf * 16 + fr][krow]);
#pragma unroll
        for (int mf = 0; mf < 4; ++mf)
#pragma unroll
            for (int nf = 0; nf < 4; ++nf)
                acc[mf][nf] = __builtin_amdgcn_mfma_f32_16x16x32_bf16(
                    af[mf], bfv[nf], acc[mf][nf], 0, 0, 0);
        __syncthreads();
    }

    const int fq = lane >> 4;
#pragma unroll
    for (int mf = 0; mf < 4; ++mf)
#pragma unroll
        for (int nf = 0; nf < 4; ++nf) {
            int col = bn + wn * 64 + nf * 16 + fr;
            float bv = bias[col];
#pragma unroll
            for (int r = 0; r < 4; ++r) {
                int row = bm + wm * 64 + mf * 16 + fq * 4 + r;
                float v = acc[mf][nf][r] + bv;
                if (F32OUT)
                    reinterpret_cast<float*>(ga.C[z])[(size_t)row * N + col] = v;
                else
                    reinterpret_cast<unsigned short*>(ga.C[z])[(size_t)row * N + col] = f2bf(v);
            }
        }
}

// ---------------- sum of V over keys, per (b,h,d) ----------------
__global__ void sumv_kernel(const unsigned short* __restrict__ Vb,
                            float* __restrict__ sumV) {
    __shared__ float r[4][HDIM];
    int bh = blockIdx.x;
    int b = bh / NHEADS, h = bh % NHEADS;
    int d = threadIdx.x & 63;
    int kc = threadIdx.x >> 6;
    float acc = 0.f;
    for (int j = kc; j < SEQ; j += 4)
        acc += bf2f(Vb[((size_t)(b * SEQ + j)) * EMBED + h * HDIM + d]);
    r[kc][d] = acc;
    __syncthreads();
    if (threadIdx.x < HDIM)
        sumV[bh * HDIM + threadIdx.x] =
            r[0][threadIdx.x] + r[1][threadIdx.x] + r[2][threadIdx.x] + r[3][threadIdx.x];
}

// ---------------- fused attention: one WAVE per q-row, no block barriers ----------------
__global__ __launch_bounds__(256) void attn_fused(
    const unsigned short* __restrict__ Q,
    const unsigned short* __restrict__ Kb,
    const unsigned short* __restrict__ Vb,
    const unsigned char* __restrict__ kpm,
    const float* __restrict__ sumV,
    float* __restrict__ attn_out,
    unsigned short* __restrict__ ctx) {
    const int wid = threadIdx.x >> 6;
    const int l = threadIdx.x & 63;
    const int row = blockIdx.x * 4 + wid;   // bh*SEQ + qi
    const int qi = row & (SEQ - 1);
    const int bh = row >> 11;
    const int h = bh % NHEADS;
    const int b = bh / NHEADS;

    const int qlo = max(qi - WIN, 0);
    const int qhi = min(qi + WIN, SEQ - 1);
    const int nk = qhi - qlo + 1;           // <= 129

    __shared__ float q_l[4][HDIM];
    __shared__ float p_l[4][136];

    const size_t qkv_base = (size_t)(b * SEQ) * EMBED + h * HDIM;

    // ---- stage q row into wave-private LDS (f32) ----
    q_l[wid][l] = bf2f(Q[qkv_base + (size_t)qi * EMBED + l]);

    // ---- scores: 2 full key slots per lane ----
    float s[2];
    bool val[2];
#pragma unroll
    for (int ks = 0; ks < 2; ++ks) {
        int j = qlo + ks * 64 + l;
        val[ks] = (j <= qhi);
        int jc = val[ks] ? j : qhi;
        const int4* kr = reinterpret_cast<const int4*>(Kb + qkv_base + (size_t)jc * EMBED);
        int4 pk[8];
#pragma unroll
        for (int c = 0; c < 8; ++c) pk[c] = kr[c];
        float acc0 = 0.f, acc1 = 0.f;
#pragma unroll
        for (int c = 0; c < 8; ++c) {
            const unsigned short* u = reinterpret_cast<const unsigned short*>(&pk[c]);
            const float* qp = &q_l[wid][c * 8];
#pragma unroll
            for (int e = 0; e < 8; e += 2) {
                acc0 += qp[e] * bf2f(u[e]);
                acc1 += qp[e + 1] * bf2f(u[e + 1]);
            }
        }
        float sv = (acc0 + acc1) * 0.125f;
        if (kpm[b * SEQ + jc]) sv = -10000.f;
        s[ks] = val[ks] ? sv : -1e30f;
    }

    // ---- 129th key (only when nk==129): cooperative dot ----
    float s2 = -1e30f;
    if (nk == 129) {
        int j = qlo + 128;
        float part = q_l[wid][l] * bf2f(Kb[qkv_base + (size_t)j * EMBED + l]);
#pragma unroll
        for (int off = 32; off; off >>= 1) part += __shfl_xor(part, off);
        s2 = part * 0.125f;
        if (kpm[b * SEQ + j]) s2 = -10000.f;
    }

    // ---- wave max ----
    float m = fmaxf(fmaxf(s[0], s[1]), s2);
#pragma unroll
    for (int off = 32; off; off >>= 1) m = fmaxf(m, __shfl_xor(m, off));

    // ---- exp & wave sum ----
    float p0 = val[0] ? __expf(s[0] - m) : 0.f;
    float p1 = val[1] ? __expf(s[1] - m) : 0.f;
    float p2 = (nk == 129) ? __expf(s2 - m) : 0.f;   // same value on all lanes
    float lsum = p0 + p1 + ((l == 0) ? p2 : 0.f);
#pragma unroll
    for (int off = 32; off; off >>= 1) lsum += __shfl_xor(lsum, off);
    const float dsum = lsum;

    // ---- normalized probs to wave-private LDS ----
    if (val[0]) p_l[wid][l] = p0 / dsum;
    if (val[1]) p_l[wid][64 + l] = p1 / dsum;
    if (nk == 129 && l == 0) p_l[wid][128] = p2 / dsum;

    // ---- write full attn row: 8 coalesced NT float4 stores per lane ----
    {
        float* __restrict__ orow = attn_out + (size_t)row * SEQ;
#pragma unroll
        for (int g = 0; g < 8; ++g) {
            int c0 = g * 256 + l * 4;
            f32x4 v = {1e-6f, 1e-6f, 1e-6f, 1e-6f};
            if (c0 + 3 >= qlo && c0 <= qhi) {
#pragma unroll
                for (int e = 0; e < 4; ++e) {
                    int c = c0 + e;
                    if (c >= qlo && c <= qhi) v[e] = p_l[wid][c - qlo] + 1e-6f;
                }
            }
            __builtin_nontemporal_store(v, reinterpret_cast<f32x4*>(orow + c0));
        }
    }

    // ---- PV: lane l owns output dim d=l ----
    {
        const unsigned short* __restrict__ vcol = Vb + qkv_base + (size_t)qlo * EMBED + l;
        float acc0 = 0.f, acc1 = 0.f;
        int j = 0;
        for (; j + 8 <= nk; j += 8) {
#pragma unroll
            for (int u = 0; u < 8; u += 2) {
                acc0 += p_l[wid][j + u] * bf2f(vcol[(size_t)(j + u) * EMBED]);
                acc1 += p_l[wid][j + u + 1] * bf2f(vcol[(size_t)(j + u + 1) * EMBED]);
            }
        }
        for (; j < nk; ++j)
            acc0 += p_l[wid][j] * bf2f(vcol[(size_t)j * EMBED]);
        float c = acc0 + acc1 + 1e-6f * sumV[bh * HDIM + l];
        ctx[qkv_base + (size_t)qi * EMBED + l] = f2bf(c);
    }
}

// ---------------- host ----------------
extern "C" void kernel_launch(void* const* d_in, const int* in_sizes, int n_in,
                              void* d_out, int out_size, void* d_ws, size_t ws_size,
                              hipStream_t stream) {
    const float* q_in = (const float*)d_in[0];
    const float* k_in = (const float*)d_in[1];
    const float* v_in = (const float*)d_in[2];
    const unsigned char* kpm = (const unsigned char*)d_in[3];
    const float* Wq = (const float*)d_in[4];
    const float* bq = (const float*)d_in[5];
    const float* Wk = (const float*)d_in[6];
    const float* bk = (const float*)d_in[7];
    const float* Wv = (const float*)d_in[8];
    const float* bv = (const float*)d_in[9];
    const float* Wo = (const float*)d_in[10];
    const float* bo = (const float*)d_in[11];

    char* ws = (char*)d_ws;
    size_t off = 0;
    auto alloc = [&](size_t bytes) {
        void* p = ws + off;
        off += (bytes + 255) & ~255ULL;
        return p;
    };
    const size_t XB = (size_t)MROWS * EMBED * 2;  // bf16 [4096,768]
    const size_t WB = (size_t)EMBED * EMBED * 2;  // bf16 [768,768]
    unsigned short* xq = (unsigned short*)alloc(XB);
    unsigned short* xk = (unsigned short*)alloc(XB);
    unsigned short* xv = (unsigned short*)alloc(XB);
    unsigned short* wqb = (unsigned short*)alloc(WB);
    unsigned short* wkb = (unsigned short*)alloc(WB);
    unsigned short* wvb = (unsigned short*)alloc(WB);
    unsigned short* wob = (unsigned short*)alloc(WB);
    unsigned short* Qb = (unsigned short*)alloc(XB);
    unsigned short* Kb = (unsigned short*)alloc(XB);
    unsigned short* Vb = (unsigned short*)alloc(XB);
    unsigned short* ctx = (unsigned short*)alloc(XB);
    float* sumV = (float*)alloc((size_t)NBH * HDIM * 4);

    float* out0 = (float*)d_out;
    float* attn_out = out0 + (size_t)MROWS * EMBED;  // [B,H,S,S]

    // ---- one fused conversion launch ----
    {
        CvtArgs ca;
        const float* srcs[7] = {q_in, k_in, v_in, Wq, Wk, Wv, Wo};
        unsigned short* dsts[7] = {xq, xk, xv, wqb, wkb, wvb, wob};
        int bacc = 0;
        for (int s = 0; s < 7; ++s) {
            ca.src[s] = srcs[s];
            ca.dst[s] = dsts[s];
            ca.n4[s] = (s < 3) ? (MROWS * EMBED / 4) : (EMBED * EMBED / 4);
            ca.bstart[s] = bacc;
            bacc += (ca.n4[s] + 255) / 256;
        }
        ca.bstart[7] = bacc;
        cvt_all<<<dim3(bacc), dim3(256), 0, stream>>>(ca);
    }

    // QKV projections (batched, z selects q/k/v)
    {
        GArgs ga;
        ga.A[0] = xq;  ga.A[1] = xk;  ga.A[2] = xv;
        ga.Bm[0] = wqb; ga.Bm[1] = wkb; ga.Bm[2] = wvb;
        ga.bias[0] = bq; ga.bias[1] = bk; ga.bias[2] = bv;
        ga.C[0] = Qb; ga.C[1] = Kb; ga.C[2] = Vb;
        gemm_nt<0><<<dim3(EMBED / 128, MROWS / 128, 3), dim3(256), 0, stream>>>(
            ga, MROWS, EMBED, EMBED);
    }

    sumv_kernel<<<dim3(NBH), dim3(256), 0, stream>>>(Vb, sumV);

    attn_fused<<<dim3(NBH * SEQ / 4), dim3(256), 0, stream>>>(
        Qb, Kb, Vb, kpm, sumV, attn_out, ctx);

    // output projection -> fp32 out
    {
        GArgs ga;
        ga.A[0] = ctx;  ga.A[1] = ctx;  ga.A[2] = ctx;
        ga.Bm[0] = wob; ga.Bm[1] = wob; ga.Bm[2] = wob;
        ga.bias[0] = bo; ga.bias[1] = bo; ga.bias[2] = bo;
        ga.C[0] = out0; ga.C[1] = out0; ga.C[2] = out0;
        gemm_nt<1><<<dim3(EMBED / 128, MROWS / 128, 1), dim3(256), 0, stream>>>(
            ga, MROWS, EMBED, EMBED);
    }
}

// Round 5
// 299.650 us; speedup vs baseline: 2.2459x; 1.3305x over previous
//
#include <hip/hip_runtime.h>
#include <hip/hip_bf16.h>

#define EMBED 768
#define NHEADS 12
#define HDIM 64
#define WIN 64
#define BATCH 2
#define SEQ 2048
#define MROWS (BATCH*SEQ)      // 4096
#define NBH (BATCH*NHEADS)     // 24
#define QT 32                  // q rows per attn block
#define KP 160                 // key panel width
#define KPAD 168               // padded LDS cols

typedef __attribute__((ext_vector_type(8))) short short8;
typedef __attribute__((ext_vector_type(4))) float f32x4;

__device__ __forceinline__ float bf2f(unsigned short u) {
    union { unsigned int i; float f; } z;
    z.i = ((unsigned int)u) << 16;
    return z.f;
}
__device__ __forceinline__ unsigned short f2bf(float f) {
    __hip_bfloat16 h = __float2bfloat16(f);
    return *reinterpret_cast<unsigned short*>(&h);
}

// ---------------- fused fp32 -> bf16 conversion (7 segments, 1 launch) ----------------
struct CvtArgs {
    const float* src[7];
    unsigned short* dst[7];
    int n4[7];
    int bstart[8];
};

__global__ __launch_bounds__(256) void cvt_all(CvtArgs ca) {
    int bid = blockIdx.x;
    int seg = 0;
#pragma unroll
    for (int s = 0; s < 6; ++s)
        if (bid >= ca.bstart[s + 1]) seg = s + 1;
    int i = (bid - ca.bstart[seg]) * 256 + threadIdx.x;
    if (i < ca.n4[seg]) {
        float4 v = reinterpret_cast<const float4*>(ca.src[seg])[i];
        ushort4 o;
        o.x = f2bf(v.x); o.y = f2bf(v.y); o.z = f2bf(v.z); o.w = f2bf(v.w);
        reinterpret_cast<ushort4*>(ca.dst[seg])[i] = o;
    }
}

// ---------------- bf16 NT GEMM: C[M,N] = A[M,K] * B[N,K]^T + bias ----------------
struct GArgs {
    const unsigned short* A[3];
    const unsigned short* Bm[3];
    const float* bias[3];
    void* C[3];
};

template<int F32OUT>
__global__ __launch_bounds__(256) void gemm_nt(GArgs ga, int M, int N, int K) {
    const int z = blockIdx.z;
    const unsigned short* __restrict__ A  = ga.A[z];
    const unsigned short* __restrict__ Bm = ga.Bm[z];
    const float* __restrict__ bias = ga.bias[z];

    const int bm = blockIdx.y * 128;
    const int bn = blockIdx.x * 128;

    __shared__ unsigned short As[128][40];
    __shared__ unsigned short Bs[128][40];

    const int tid = threadIdx.x;
    const int lane = tid & 63;
    const int wid = tid >> 6;
    const int wm = wid >> 1, wn = wid & 1;

    f32x4 acc[4][4] = {};

    const int fr = lane & 15;
    const int krow = (lane >> 4) * 8;

    for (int k0 = 0; k0 < K; k0 += 32) {
#pragma unroll
        for (int it = 0; it < 2; ++it) {
            int idx = tid + it * 256;
            int r = idx >> 2;
            int c = (idx & 3) * 8;
            int4 av = *reinterpret_cast<const int4*>(A + (size_t)(bm + r) * K + k0 + c);
            *reinterpret_cast<int4*>(&As[r][c]) = av;
            int4 bv = *reinterpret_cast<const int4*>(Bm + (size_t)(bn + r) * K + k0 + c);
            *reinterpret_cast<int4*>(&Bs[r][c]) = bv;
        }
        __syncthreads();

        short8 af[4], bfv[4];
#pragma unroll
        for (int mf = 0; mf < 4; ++mf)
            af[mf] = *reinterpret_cast<const short8*>(&As[wm * 64 + mf * 16 + fr][krow]);
#pragma unroll
        for (int nf = 0; nf < 4; ++nf)
            bfv[nf] = *reinterpret_cast<const short8*>(&Bs[wn * 64 + nf * 16 + fr][krow]);
#pragma unroll
        for (int mf = 0; mf < 4; ++mf)
#pragma unroll
            for (int nf = 0; nf < 4; ++nf)
                acc[mf][nf] = __builtin_amdgcn_mfma_f32_16x16x32_bf16(
                    af[mf], bfv[nf], acc[mf][nf], 0, 0, 0);
        __syncthreads();
    }

    const int fq = lane >> 4;
#pragma unroll
    for (int mf = 0; mf < 4; ++mf)
#pragma unroll
        for (int nf = 0; nf < 4; ++nf) {
            int col = bn + wn * 64 + nf * 16 + fr;
            float bv = bias[col];
#pragma unroll
            for (int r = 0; r < 4; ++r) {
                int row = bm + wm * 64 + mf * 16 + fq * 4 + r;
                float v = acc[mf][nf][r] + bv;
                if (F32OUT)
                    reinterpret_cast<float*>(ga.C[z])[(size_t)row * N + col] = v;
                else
                    reinterpret_cast<unsigned short*>(ga.C[z])[(size_t)row * N + col] = f2bf(v);
            }
        }
}

// ---------------- sum of V over keys, per (b,h,d) ----------------
__global__ void sumv_kernel(const unsigned short* __restrict__ Vb,
                            float* __restrict__ sumV) {
    __shared__ float r[4][HDIM];
    int bh = blockIdx.x;
    int b = bh / NHEADS, h = bh % NHEADS;
    int d = threadIdx.x & 63;
    int kc = threadIdx.x >> 6;
    float acc = 0.f;
    for (int j = kc; j < SEQ; j += 4)
        acc += bf2f(Vb[((size_t)(b * SEQ + j)) * EMBED + h * HDIM + d]);
    r[kc][d] = acc;
    __syncthreads();
    if (threadIdx.x < HDIM)
        sumV[bh * HDIM + threadIdx.x] =
            r[0][threadIdx.x] + r[1][threadIdx.x] + r[2][threadIdx.x] + r[3][threadIdx.x];
}

// ---------------- MFMA-tile attention: 32 q-rows per block ----------------
__global__ __launch_bounds__(256) void attn_mfma(
    const unsigned short* __restrict__ Q,
    const unsigned short* __restrict__ Kb,
    const unsigned short* __restrict__ Vb,
    const unsigned char* __restrict__ kpm,
    const float* __restrict__ sumV,
    float* __restrict__ attn_out,
    unsigned short* __restrict__ ctx) {
    const int qt = blockIdx.x;          // 0..SEQ/QT-1
    const int bh = blockIdx.y;          // 0..NBH-1
    const int h = bh % NHEADS;
    const int b = bh / NHEADS;
    const int q0 = qt * QT;
    const int kstart = max(q0 - WIN, 0);

    __shared__ float Sf[QT][KPAD];            // scores, then probs (f32)
    __shared__ unsigned short Pb[QT][KPAD];   // probs bf16
    __shared__ unsigned short Vt[HDIM][KPAD]; // V transposed

    const int tid = threadIdx.x;
    const int l = tid & 63;
    const int w = tid >> 6;
    const int fr = l & 15;
    const int ksl = (l >> 4) * 8;

    const size_t base = (size_t)(b * SEQ) * EMBED + h * HDIM;

    // ======== Phase A: scores via MFMA + Vt staging ========
    {
        const int mf = w >> 1;              // M-tile 0..1
        const int nt0 = (w & 1) * 5;        // N-tiles [nt0, nt0+5)

        // A fragments (Q rows)
        const unsigned short* qrow = Q + base + (size_t)(q0 + mf * 16 + fr) * EMBED;
        short8 aq0 = *reinterpret_cast<const short8*>(qrow + ksl);
        short8 aq1 = *reinterpret_cast<const short8*>(qrow + 32 + ksl);

        f32x4 sacc[5] = {};
#pragma unroll
        for (int t = 0; t < 5; ++t) {
            int jg = kstart + (nt0 + t) * 16 + fr;
            int jc = min(jg, SEQ - 1);
            const unsigned short* krow = Kb + base + (size_t)jc * EMBED;
            short8 b0 = *reinterpret_cast<const short8*>(krow + ksl);
            short8 b1 = *reinterpret_cast<const short8*>(krow + 32 + ksl);
            sacc[t] = __builtin_amdgcn_mfma_f32_16x16x32_bf16(aq0, b0, sacc[t], 0, 0, 0);
            sacc[t] = __builtin_amdgcn_mfma_f32_16x16x32_bf16(aq1, b1, sacc[t], 0, 0, 0);
        }

        // masked write S -> LDS
#pragma unroll
        for (int t = 0; t < 5; ++t) {
            int col = (nt0 + t) * 16 + fr;
            int jg = kstart + col;
            bool jvalid = (jg < SEQ);
            bool mk = jvalid && kpm[b * SEQ + jg];
#pragma unroll
            for (int r = 0; r < 4; ++r) {
                int rowl = mf * 16 + (l >> 4) * 4 + r;
                int qi = q0 + rowl;
                float s = sacc[t][r] * 0.125f;
                if (mk) s = -10000.f;
                int dd = qi - jg;
                if (!jvalid || dd > WIN || dd < -WIN) s = -1e30f;
                Sf[rowl][col] = s;
            }
        }

        // Vt staging: Vt[d][jrel] = V[kstart+jrel][d]
#pragma unroll
        for (int it = 0; it < KP / 4; ++it) {
            int jrel = it * 4 + w;
            int jg = kstart + jrel;
            unsigned short vv = 0;
            if (jg < SEQ) vv = Vb[base + (size_t)jg * EMBED + l];
            Vt[l][jrel] = vv;
        }
    }
    __syncthreads();

    // ======== Phase B: row softmax (8 threads per row) ========
    {
        const int row = tid >> 3;           // 0..31
        const int cg = tid & 7;
        float e[KP / 8];
        float m = -1e30f;
#pragma unroll
        for (int i = 0; i < KP / 8; ++i) {
            float s = Sf[row][cg + i * 8];
            e[i] = s;
            m = fmaxf(m, s);
        }
#pragma unroll
        for (int off = 1; off < 8; off <<= 1) m = fmaxf(m, __shfl_xor(m, off));
        float sum = 0.f;
#pragma unroll
        for (int i = 0; i < KP / 8; ++i) {
            e[i] = __expf(e[i] - m);
            sum += e[i];
        }
#pragma unroll
        for (int off = 1; off < 8; off <<= 1) sum += __shfl_xor(sum, off);
        float inv = 1.f / sum;
#pragma unroll
        for (int i = 0; i < KP / 8; ++i) {
            float p = e[i] * inv;
            int col = cg + i * 8;
            Sf[row][col] = p;
            Pb[row][col] = f2bf(p);
        }
    }
    __syncthreads();

    // ======== Phase C: PV via MFMA -> ctx ========
    {
        const int mf = w >> 1;              // q tile 0..1
        const int nfb = (w & 1) * 2;        // d tiles {nfb, nfb+1}
        f32x4 oacc[2] = {};
#pragma unroll
        for (int kk = 0; kk < KP / 32; ++kk) {
            short8 a = *reinterpret_cast<const short8*>(&Pb[mf * 16 + fr][kk * 32 + ksl]);
#pragma unroll
            for (int n2 = 0; n2 < 2; ++n2) {
                short8 bv = *reinterpret_cast<const short8*>(&Vt[(nfb + n2) * 16 + fr][kk * 32 + ksl]);
                oacc[n2] = __builtin_amdgcn_mfma_f32_16x16x32_bf16(a, bv, oacc[n2], 0, 0, 0);
            }
        }
#pragma unroll
        for (int n2 = 0; n2 < 2; ++n2) {
            int d = (nfb + n2) * 16 + fr;
            float sv = 1e-6f * sumV[bh * HDIM + d];
#pragma unroll
            for (int r = 0; r < 4; ++r) {
                int rowl = mf * 16 + (l >> 4) * 4 + r;
                ctx[base + (size_t)(q0 + rowl) * EMBED + d] = f2bf(oacc[n2][r] + sv);
            }
        }
    }

    // ======== Phase D: stream full attn rows (NT stores) ========
    {
#pragma unroll
        for (int rr = 0; rr < QT / 4; ++rr) {
            int row = w * (QT / 4) + rr;
            int qi = q0 + row;
            int blo = max(qi - WIN, 0);
            int bhi = min(qi + WIN, SEQ - 1);
            float* __restrict__ orow = attn_out + ((size_t)bh * SEQ + qi) * SEQ;
#pragma unroll
            for (int seg = 0; seg < SEQ / 256; ++seg) {
                int c0 = seg * 256 + l * 4;
                f32x4 v = {1e-6f, 1e-6f, 1e-6f, 1e-6f};
                if (c0 + 3 >= blo && c0 <= bhi) {
#pragma unroll
                    for (int e = 0; e < 4; ++e) {
                        int c = c0 + e;
                        if (c >= blo && c <= bhi) v[e] = Sf[row][c - kstart] + 1e-6f;
                    }
                }
                __builtin_nontemporal_store(v, reinterpret_cast<f32x4*>(orow + c0));
            }
        }
    }
}

// ---------------- host ----------------
extern "C" void kernel_launch(void* const* d_in, const int* in_sizes, int n_in,
                              void* d_out, int out_size, void* d_ws, size_t ws_size,
                              hipStream_t stream) {
    const float* q_in = (const float*)d_in[0];
    const float* k_in = (const float*)d_in[1];
    const float* v_in = (const float*)d_in[2];
    const unsigned char* kpm = (const unsigned char*)d_in[3];
    const float* Wq = (const float*)d_in[4];
    const float* bq = (const float*)d_in[5];
    const float* Wk = (const float*)d_in[6];
    const float* bk = (const float*)d_in[7];
    const float* Wv = (const float*)d_in[8];
    const float* bv = (const float*)d_in[9];
    const float* Wo = (const float*)d_in[10];
    const float* bo = (const float*)d_in[11];

    char* ws = (char*)d_ws;
    size_t off = 0;
    auto alloc = [&](size_t bytes) {
        void* p = ws + off;
        off += (bytes + 255) & ~255ULL;
        return p;
    };
    const size_t XB = (size_t)MROWS * EMBED * 2;
    const size_t WB = (size_t)EMBED * EMBED * 2;
    unsigned short* xq = (unsigned short*)alloc(XB);
    unsigned short* xk = (unsigned short*)alloc(XB);
    unsigned short* xv = (unsigned short*)alloc(XB);
    unsigned short* wqb = (unsigned short*)alloc(WB);
    unsigned short* wkb = (unsigned short*)alloc(WB);
    unsigned short* wvb = (unsigned short*)alloc(WB);
    unsigned short* wob = (unsigned short*)alloc(WB);
    unsigned short* Qb = (unsigned short*)alloc(XB);
    unsigned short* Kb = (unsigned short*)alloc(XB);
    unsigned short* Vb = (unsigned short*)alloc(XB);
    unsigned short* ctx = (unsigned short*)alloc(XB);
    float* sumV = (float*)alloc((size_t)NBH * HDIM * 4);

    float* out0 = (float*)d_out;
    float* attn_out = out0 + (size_t)MROWS * EMBED;

    // ---- one fused conversion launch ----
    {
        CvtArgs ca;
        const float* srcs[7] = {q_in, k_in, v_in, Wq, Wk, Wv, Wo};
        unsigned short* dsts[7] = {xq, xk, xv, wqb, wkb, wvb, wob};
        int bacc = 0;
        for (int s = 0; s < 7; ++s) {
            ca.src[s] = srcs[s];
            ca.dst[s] = dsts[s];
            ca.n4[s] = (s < 3) ? (MROWS * EMBED / 4) : (EMBED * EMBED / 4);
            ca.bstart[s] = bacc;
            bacc += (ca.n4[s] + 255) / 256;
        }
        ca.bstart[7] = bacc;
        cvt_all<<<dim3(bacc), dim3(256), 0, stream>>>(ca);
    }

    // QKV projections
    {
        GArgs ga;
        ga.A[0] = xq;  ga.A[1] = xk;  ga.A[2] = xv;
        ga.Bm[0] = wqb; ga.Bm[1] = wkb; ga.Bm[2] = wvb;
        ga.bias[0] = bq; ga.bias[1] = bk; ga.bias[2] = bv;
        ga.C[0] = Qb; ga.C[1] = Kb; ga.C[2] = Vb;
        gemm_nt<0><<<dim3(EMBED / 128, MROWS / 128, 3), dim3(256), 0, stream>>>(
            ga, MROWS, EMBED, EMBED);
    }

    sumv_kernel<<<dim3(NBH), dim3(256), 0, stream>>>(Vb, sumV);

    attn_mfma<<<dim3(SEQ / QT, NBH), dim3(256), 0, stream>>>(
        Qb, Kb, Vb, kpm, sumV, attn_out, ctx);

    // output projection -> fp32 out
    {
        GArgs ga;
        ga.A[0] = ctx;  ga.A[1] = ctx;  ga.A[2] = ctx;
        ga.Bm[0] = wob; ga.Bm[1] = wob; ga.Bm[2] = wob;
        ga.bias[0] = bo; ga.bias[1] = bo; ga.bias[2] = bo;
        ga.C[0] = out0; ga.C[1] = out0; ga.C[2] = out0;
        gemm_nt<1><<<dim3(EMBED / 128, MROWS / 128, 1), dim3(256), 0, stream>>>(
            ga, MROWS, EMBED, EMBED);
    }
}

// Round 6
// 194.750 us; speedup vs baseline: 3.4556x; 1.5386x over previous
//
#include <hip/hip_runtime.h>
#include <hip/hip_bf16.h>

#define EMBED 768
#define NHEADS 12
#define HDIM 64
#define WIN 64
#define BATCH 2
#define SEQ 2048
#define MROWS (BATCH*SEQ)      // 4096
#define NBH (BATCH*NHEADS)     // 24
#define QT 32                  // q rows per attn block
#define KP 160                 // key panel width
#define KPAD 168               // padded LDS cols (bf16 arrays, 336 B rows: 16B aligned)
#define SPAD 164               // f32 score row stride (656 B rows)

typedef __attribute__((ext_vector_type(8))) short short8;
typedef __attribute__((ext_vector_type(4))) float f32x4;

__device__ __forceinline__ float bf2f(unsigned short u) {
    union { unsigned int i; float f; } z;
    z.i = ((unsigned int)u) << 16;
    return z.f;
}
__device__ __forceinline__ unsigned short f2bf(float f) {
    __hip_bfloat16 h = __float2bfloat16(f);
    return *reinterpret_cast<unsigned short*>(&h);
}

// ---------------- fused fp32 -> bf16 conversion (7 segments, 1 launch) ----------------
struct CvtArgs {
    const float* src[7];
    unsigned short* dst[7];
    int n4[7];
    int bstart[8];
};

__global__ __launch_bounds__(256) void cvt_all(CvtArgs ca) {
    int bid = blockIdx.x;
    int seg = 0;
#pragma unroll
    for (int s = 0; s < 6; ++s)
        if (bid >= ca.bstart[s + 1]) seg = s + 1;
    int i = (bid - ca.bstart[seg]) * 256 + threadIdx.x;
    if (i < ca.n4[seg]) {
        float4 v = reinterpret_cast<const float4*>(ca.src[seg])[i];
        ushort4 o;
        o.x = f2bf(v.x); o.y = f2bf(v.y); o.z = f2bf(v.z); o.w = f2bf(v.w);
        reinterpret_cast<ushort4*>(ca.dst[seg])[i] = o;
    }
}

// ---------------- bf16 NT GEMM: C[M,N] = A[M,K] * B[N,K]^T + bias ----------------
struct GArgs {
    const unsigned short* A[3];
    const unsigned short* Bm[3];
    const float* bias[3];
    void* C[3];
};

template<int F32OUT>
__global__ __launch_bounds__(256) void gemm_nt(GArgs ga, int M, int N, int K) {
    const int z = blockIdx.z;
    const unsigned short* __restrict__ A  = ga.A[z];
    const unsigned short* __restrict__ Bm = ga.Bm[z];
    const float* __restrict__ bias = ga.bias[z];

    const int bm = blockIdx.y * 128;
    const int bn = blockIdx.x * 128;

    __shared__ unsigned short As[128][40];
    __shared__ unsigned short Bs[128][40];

    const int tid = threadIdx.x;
    const int lane = tid & 63;
    const int wid = tid >> 6;
    const int wm = wid >> 1, wn = wid & 1;

    f32x4 acc[4][4] = {};

    const int fr = lane & 15;
    const int krow = (lane >> 4) * 8;

    for (int k0 = 0; k0 < K; k0 += 32) {
#pragma unroll
        for (int it = 0; it < 2; ++it) {
            int idx = tid + it * 256;
            int r = idx >> 2;
            int c = (idx & 3) * 8;
            int4 av = *reinterpret_cast<const int4*>(A + (size_t)(bm + r) * K + k0 + c);
            *reinterpret_cast<int4*>(&As[r][c]) = av;
            int4 bv = *reinterpret_cast<const int4*>(Bm + (size_t)(bn + r) * K + k0 + c);
            *reinterpret_cast<int4*>(&Bs[r][c]) = bv;
        }
        __syncthreads();

        short8 af[4], bfv[4];
#pragma unroll
        for (int mf = 0; mf < 4; ++mf)
            af[mf] = *reinterpret_cast<const short8*>(&As[wm * 64 + mf * 16 + fr][krow]);
#pragma unroll
        for (int nf = 0; nf < 4; ++nf)
            bfv[nf] = *reinterpret_cast<const short8*>(&Bs[wn * 64 + nf * 16 + fr][krow]);
#pragma unroll
        for (int mf = 0; mf < 4; ++mf)
#pragma unroll
            for (int nf = 0; nf < 4; ++nf)
                acc[mf][nf] = __builtin_amdgcn_mfma_f32_16x16x32_bf16(
                    af[mf], bfv[nf], acc[mf][nf], 0, 0, 0);
        __syncthreads();
    }

    const int fq = lane >> 4;
#pragma unroll
    for (int mf = 0; mf < 4; ++mf)
#pragma unroll
        for (int nf = 0; nf < 4; ++nf) {
            int col = bn + wn * 64 + nf * 16 + fr;
            float bv = bias[col];
#pragma unroll
            for (int r = 0; r < 4; ++r) {
                int row = bm + wm * 64 + mf * 16 + fq * 4 + r;
                float v = acc[mf][nf][r] + bv;
                if (F32OUT)
                    reinterpret_cast<float*>(ga.C[z])[(size_t)row * N + col] = v;
                else
                    reinterpret_cast<unsigned short*>(ga.C[z])[(size_t)row * N + col] = f2bf(v);
            }
        }
}

// ---------------- sum of V over keys, per (b,h,d) — vectorized ----------------
__global__ __launch_bounds__(256) void sumv_kernel(const unsigned short* __restrict__ Vb,
                                                   float* __restrict__ sumV) {
    __shared__ float r[32][HDIM];
    const int bh = blockIdx.x;
    const int b = bh / NHEADS, h = bh % NHEADS;
    const int dg = (threadIdx.x & 7) * 8;   // 8 d's per thread
    const int r0 = threadIdx.x >> 3;        // 32 row-phases
    float acc[8] = {};
    const unsigned short* vp = Vb + (size_t)(b * SEQ) * EMBED + h * HDIM + dg;
    for (int j = r0; j < SEQ; j += 32) {
        short8 v = *reinterpret_cast<const short8*>(vp + (size_t)j * EMBED);
#pragma unroll
        for (int e = 0; e < 8; ++e)
            acc[e] += bf2f(((const unsigned short*)&v)[e]);
    }
#pragma unroll
    for (int e = 0; e < 8; ++e) r[r0][dg + e] = acc[e];
    __syncthreads();
    if (threadIdx.x < HDIM) {
        float s = 0.f;
#pragma unroll
        for (int i = 0; i < 32; ++i) s += r[i][threadIdx.x];
        sumV[bh * HDIM + threadIdx.x] = s;
    }
}

// ---------------- MFMA-tile attention: 32 q-rows per block ----------------
__global__ __launch_bounds__(256, 3) void attn_mfma(
    const unsigned short* __restrict__ Q,
    const unsigned short* __restrict__ Kb,
    const unsigned short* __restrict__ Vb,
    const unsigned char* __restrict__ kpm,
    const float* __restrict__ sumV,
    float* __restrict__ attn_out,
    unsigned short* __restrict__ ctx) {
    const int qt = blockIdx.x;
    const int bh = blockIdx.y;
    const int h = bh % NHEADS;
    const int b = bh / NHEADS;
    const int q0 = qt * QT;
    const int kstart = max(q0 - WIN, 0);

    __shared__ float Sf[QT][SPAD];            // scores, then probs (f32)
    __shared__ unsigned short Pb[QT][KPAD];   // probs bf16
    __shared__ unsigned short Vt[HDIM][KPAD]; // V transposed

    const int tid = threadIdx.x;
    const int l = tid & 63;
    const int w = tid >> 6;
    const int fr = l & 15;
    const int ksl = (l >> 4) * 8;

    const size_t base = (size_t)(b * SEQ) * EMBED + h * HDIM;

    // ======== Phase A: scores via MFMA + Vt staging ========
    {
        const int mf = w >> 1;              // M-tile 0..1
        const int nt0 = (w & 1) * 5;        // N-tiles [nt0, nt0+5)

        const unsigned short* qrow = Q + base + (size_t)(q0 + mf * 16 + fr) * EMBED;
        short8 aq0 = *reinterpret_cast<const short8*>(qrow + ksl);
        short8 aq1 = *reinterpret_cast<const short8*>(qrow + 32 + ksl);

        f32x4 sacc[5] = {};
#pragma unroll
        for (int t = 0; t < 5; ++t) {
            int jg = kstart + (nt0 + t) * 16 + fr;
            int jc = min(jg, SEQ - 1);
            const unsigned short* krow = Kb + base + (size_t)jc * EMBED;
            short8 b0 = *reinterpret_cast<const short8*>(krow + ksl);
            short8 b1 = *reinterpret_cast<const short8*>(krow + 32 + ksl);
            sacc[t] = __builtin_amdgcn_mfma_f32_16x16x32_bf16(aq0, b0, sacc[t], 0, 0, 0);
            sacc[t] = __builtin_amdgcn_mfma_f32_16x16x32_bf16(aq1, b1, sacc[t], 0, 0, 0);
        }

#pragma unroll
        for (int t = 0; t < 5; ++t) {
            int col = (nt0 + t) * 16 + fr;
            int jg = kstart + col;
            bool jvalid = (jg < SEQ);
            bool mk = jvalid && kpm[b * SEQ + jg];
#pragma unroll
            for (int r = 0; r < 4; ++r) {
                int rowl = mf * 16 + (l >> 4) * 4 + r;
                int qi = q0 + rowl;
                float s = sacc[t][r] * 0.125f;
                if (mk) s = -10000.f;
                int dd = qi - jg;
                if (!jvalid || dd > WIN || dd < -WIN) s = -1e30f;
                Sf[rowl][col] = s;
            }
        }

        // Vt staging: Vt[d][jrel] = V[kstart+jrel][d]
#pragma unroll
        for (int it = 0; it < KP / 4; ++it) {
            int jrel = it * 4 + w;
            int jg = kstart + jrel;
            unsigned short vv = 0;
            if (jg < SEQ) vv = Vb[base + (size_t)jg * EMBED + l];
            Vt[l][jrel] = vv;
        }
    }
    __syncthreads();

    // ======== Phase B: row softmax (8 threads per row) ========
    {
        const int row = tid >> 3;
        const int cg = tid & 7;
        float e[KP / 8];
        float m = -1e30f;
#pragma unroll
        for (int i = 0; i < KP / 8; ++i) {
            float s = Sf[row][cg + i * 8];
            e[i] = s;
            m = fmaxf(m, s);
        }
#pragma unroll
        for (int off = 1; off < 8; off <<= 1) m = fmaxf(m, __shfl_xor(m, off));
        float sum = 0.f;
#pragma unroll
        for (int i = 0; i < KP / 8; ++i) {
            e[i] = __expf(e[i] - m);
            sum += e[i];
        }
#pragma unroll
        for (int off = 1; off < 8; off <<= 1) sum += __shfl_xor(sum, off);
        float inv = 1.f / sum;
#pragma unroll
        for (int i = 0; i < KP / 8; ++i) {
            float p = e[i] * inv;
            int col = cg + i * 8;
            Sf[row][col] = p;
            Pb[row][col] = f2bf(p);
        }
    }
    __syncthreads();

    // ======== Phase D (early): stream full attn rows (NT stores) ========
    // Issued BEFORE PV so the store burst drains under the MFMA work.
    {
#pragma unroll
        for (int rr = 0; rr < QT / 4; ++rr) {
            int row = w * (QT / 4) + rr;
            int qi = q0 + row;
            int blo = max(qi - WIN, 0);
            int bhi = min(qi + WIN, SEQ - 1);
            float* __restrict__ orow = attn_out + ((size_t)bh * SEQ + qi) * SEQ;
#pragma unroll
            for (int seg = 0; seg < SEQ / 256; ++seg) {
                int c0 = seg * 256 + l * 4;
                f32x4 v = {1e-6f, 1e-6f, 1e-6f, 1e-6f};
                if (c0 + 3 >= blo && c0 <= bhi) {
#pragma unroll
                    for (int e = 0; e < 4; ++e) {
                        int c = c0 + e;
                        if (c >= blo && c <= bhi) v[e] = Sf[row][c - kstart] + 1e-6f;
                    }
                }
                __builtin_nontemporal_store(v, reinterpret_cast<f32x4*>(orow + c0));
            }
        }
    }

    // ======== Phase C: PV via MFMA -> ctx ========
    {
        const int mf = w >> 1;
        const int nfb = (w & 1) * 2;
        f32x4 oacc[2] = {};
#pragma unroll
        for (int kk = 0; kk < KP / 32; ++kk) {
            short8 a = *reinterpret_cast<const short8*>(&Pb[mf * 16 + fr][kk * 32 + ksl]);
#pragma unroll
            for (int n2 = 0; n2 < 2; ++n2) {
                short8 bv = *reinterpret_cast<const short8*>(&Vt[(nfb + n2) * 16 + fr][kk * 32 + ksl]);
                oacc[n2] = __builtin_amdgcn_mfma_f32_16x16x32_bf16(a, bv, oacc[n2], 0, 0, 0);
            }
        }
#pragma unroll
        for (int n2 = 0; n2 < 2; ++n2) {
            int d = (nfb + n2) * 16 + fr;
            float sv = 1e-6f * sumV[bh * HDIM + d];
#pragma unroll
            for (int r = 0; r < 4; ++r) {
                int rowl = mf * 16 + (l >> 4) * 4 + r;
                ctx[base + (size_t)(q0 + rowl) * EMBED + d] = f2bf(oacc[n2][r] + sv);
            }
        }
    }
}

// ---------------- host ----------------
extern "C" void kernel_launch(void* const* d_in, const int* in_sizes, int n_in,
                              void* d_out, int out_size, void* d_ws, size_t ws_size,
                              hipStream_t stream) {
    const float* q_in = (const float*)d_in[0];
    const float* k_in = (const float*)d_in[1];
    const float* v_in = (const float*)d_in[2];
    const unsigned char* kpm = (const unsigned char*)d_in[3];
    const float* Wq = (const float*)d_in[4];
    const float* bq = (const float*)d_in[5];
    const float* Wk = (const float*)d_in[6];
    const float* bk = (const float*)d_in[7];
    const float* Wv = (const float*)d_in[8];
    const float* bv = (const float*)d_in[9];
    const float* Wo = (const float*)d_in[10];
    const float* bo = (const float*)d_in[11];

    char* ws = (char*)d_ws;
    size_t off = 0;
    auto alloc = [&](size_t bytes) {
        void* p = ws + off;
        off += (bytes + 255) & ~255ULL;
        return p;
    };
    const size_t XB = (size_t)MROWS * EMBED * 2;
    const size_t WB = (size_t)EMBED * EMBED * 2;
    unsigned short* xq = (unsigned short*)alloc(XB);
    unsigned short* xk = (unsigned short*)alloc(XB);
    unsigned short* xv = (unsigned short*)alloc(XB);
    unsigned short* wqb = (unsigned short*)alloc(WB);
    unsigned short* wkb = (unsigned short*)alloc(WB);
    unsigned short* wvb = (unsigned short*)alloc(WB);
    unsigned short* wob = (unsigned short*)alloc(WB);
    unsigned short* Qb = (unsigned short*)alloc(XB);
    unsigned short* Kb = (unsigned short*)alloc(XB);
    unsigned short* Vb = (unsigned short*)alloc(XB);
    unsigned short* ctx = (unsigned short*)alloc(XB);
    float* sumV = (float*)alloc((size_t)NBH * HDIM * 4);

    float* out0 = (float*)d_out;
    float* attn_out = out0 + (size_t)MROWS * EMBED;

    // ---- one fused conversion launch ----
    {
        CvtArgs ca;
        const float* srcs[7] = {q_in, k_in, v_in, Wq, Wk, Wv, Wo};
        unsigned short* dsts[7] = {xq, xk, xv, wqb, wkb, wvb, wob};
        int bacc = 0;
        for (int s = 0; s < 7; ++s) {
            ca.src[s] = srcs[s];
            ca.dst[s] = dsts[s];
            ca.n4[s] = (s < 3) ? (MROWS * EMBED / 4) : (EMBED * EMBED / 4);
            ca.bstart[s] = bacc;
            bacc += (ca.n4[s] + 255) / 256;
        }
        ca.bstart[7] = bacc;
        cvt_all<<<dim3(bacc), dim3(256), 0, stream>>>(ca);
    }

    // QKV projections
    {
        GArgs ga;
        ga.A[0] = xq;  ga.A[1] = xk;  ga.A[2] = xv;
        ga.Bm[0] = wqb; ga.Bm[1] = wkb; ga.Bm[2] = wvb;
        ga.bias[0] = bq; ga.bias[1] = bk; ga.bias[2] = bv;
        ga.C[0] = Qb; ga.C[1] = Kb; ga.C[2] = Vb;
        gemm_nt<0><<<dim3(EMBED / 128, MROWS / 128, 3), dim3(256), 0, stream>>>(
            ga, MROWS, EMBED, EMBED);
    }

    sumv_kernel<<<dim3(NBH), dim3(256), 0, stream>>>(Vb, sumV);

    attn_mfma<<<dim3(SEQ / QT, NBH), dim3(256), 0, stream>>>(
        Qb, Kb, Vb, kpm, sumV, attn_out, ctx);

    // output projection -> fp32 out
    {
        GArgs ga;
        ga.A[0] = ctx;  ga.A[1] = ctx;  ga.A[2] = ctx;
        ga.Bm[0] = wob; ga.Bm[1] = wob; ga.Bm[2] = wob;
        ga.bias[0] = bo; ga.bias[1] = bo; ga.bias[2] = bo;
        ga.C[0] = out0; ga.C[1] = out0; ga.C[2] = out0;
        gemm_nt<1><<<dim3(EMBED / 128, MROWS / 128, 1), dim3(256), 0, stream>>>(
            ga, MROWS, EMBED, EMBED);
    }
}

// Round 7
// 176.776 us; speedup vs baseline: 3.8069x; 1.1017x over previous
//
#include <hip/hip_runtime.h>
#include <hip/hip_bf16.h>

#define EMBED 768
#define NHEADS 12
#define HDIM 64
#define WIN 64
#define BATCH 2
#define SEQ 2048
#define MROWS (BATCH*SEQ)      // 4096
#define NBH (BATCH*NHEADS)     // 24
#define QT 32                  // q rows per attn block
#define KP 160                 // key panel width
#define KPAD 168               // padded LDS cols (bf16 arrays, 336 B rows: 16B aligned)
#define SPAD 164               // f32 score row stride

typedef __attribute__((ext_vector_type(8))) short short8;
typedef __attribute__((ext_vector_type(4))) float f32x4;

__device__ __forceinline__ float bf2f(unsigned short u) {
    union { unsigned int i; float f; } z;
    z.i = ((unsigned int)u) << 16;
    return z.f;
}
__device__ __forceinline__ unsigned short f2bf(float f) {
    __hip_bfloat16 h = __float2bfloat16(f);
    return *reinterpret_cast<unsigned short*>(&h);
}

// async global->LDS, 16 B per lane; LDS dest must be waveBase + lane*16
__device__ __forceinline__ void gload16(const unsigned short* g, unsigned short* l) {
    __builtin_amdgcn_global_load_lds(
        (const __attribute__((address_space(1))) unsigned int*)g,
        (__attribute__((address_space(3))) unsigned int*)l,
        16, 0, 0);
}

// ---------------- fused fp32 -> bf16 conversion (7 segments, 1 launch) ----------------
struct CvtArgs {
    const float* src[7];
    unsigned short* dst[7];
    int n4[7];
    int bstart[8];
};

__global__ __launch_bounds__(256) void cvt_all(CvtArgs ca) {
    int bid = blockIdx.x;
    int seg = 0;
#pragma unroll
    for (int s = 0; s < 6; ++s)
        if (bid >= ca.bstart[s + 1]) seg = s + 1;
    int i = (bid - ca.bstart[seg]) * 256 + threadIdx.x;
    if (i < ca.n4[seg]) {
        float4 v = reinterpret_cast<const float4*>(ca.src[seg])[i];
        ushort4 o;
        o.x = f2bf(v.x); o.y = f2bf(v.y); o.z = f2bf(v.z); o.w = f2bf(v.w);
        reinterpret_cast<ushort4*>(ca.dst[seg])[i] = o;
    }
}

// ---------------- bf16 NT GEMM: C[M,N] = A[M,K] * B[N,K]^T + bias ----------------
// m97-style: global_load_lds width-16 staging into linear LDS tiles.
struct GArgs {
    const unsigned short* A[3];
    const unsigned short* Bm[3];
    const float* bias[3];
    void* C[3];
};

template<int F32OUT>
__global__ __launch_bounds__(256) void gemm_nt(GArgs ga, int M, int N, int K) {
    const int z = blockIdx.z;
    const unsigned short* __restrict__ A  = ga.A[z];
    const unsigned short* __restrict__ Bm = ga.Bm[z];
    const float* __restrict__ bias = ga.bias[z];

    const int bm = blockIdx.y * 128;
    const int bn = blockIdx.x * 128;

    __shared__ unsigned short As[128 * 32];   // linear, 16B chunks lane-contiguous
    __shared__ unsigned short Bs[128 * 32];

    const int tid = threadIdx.x;
    const int lane = tid & 63;
    const int wid = tid >> 6;
    const int wm = wid >> 1, wn = wid & 1;

    f32x4 acc[4][4] = {};

    const int fr = lane & 15;
    const int krow = (lane >> 4) * 8;

    for (int k0 = 0; k0 < K; k0 += 32) {
        // stage A,B tiles: chunk idx = it*256+tid -> row=idx>>2, col=(idx&3)*8
#pragma unroll
        for (int it = 0; it < 2; ++it) {
            int idx = it * 256 + tid;
            int r = idx >> 2;
            int c = (idx & 3) * 8;
            gload16(A + (size_t)(bm + r) * K + k0 + c, &As[idx * 8]);
            gload16(Bm + (size_t)(bn + r) * K + k0 + c, &Bs[idx * 8]);
        }
        __syncthreads();   // drains vmcnt (incl. global_load_lds)

        short8 af[4], bfv[4];
#pragma unroll
        for (int mf = 0; mf < 4; ++mf)
            af[mf] = *reinterpret_cast<const short8*>(&As[(wm * 64 + mf * 16 + fr) * 32 + krow]);
#pragma unroll
        for (int nf = 0; nf < 4; ++nf)
            bfv[nf] = *reinterpret_cast<const short8*>(&Bs[(wn * 64 + nf * 16 + fr) * 32 + krow]);
#pragma unroll
        for (int mf = 0; mf < 4; ++mf)
#pragma unroll
            for (int nf = 0; nf < 4; ++nf)
                acc[mf][nf] = __builtin_amdgcn_mfma_f32_16x16x32_bf16(
                    af[mf], bfv[nf], acc[mf][nf], 0, 0, 0);
        __syncthreads();
    }

    const int fq = lane >> 4;
#pragma unroll
    for (int mf = 0; mf < 4; ++mf)
#pragma unroll
        for (int nf = 0; nf < 4; ++nf) {
            int col = bn + wn * 64 + nf * 16 + fr;
            float bv = bias[col];
#pragma unroll
            for (int r = 0; r < 4; ++r) {
                int row = bm + wm * 64 + mf * 16 + fq * 4 + r;
                float v = acc[mf][nf][r] + bv;
                if (F32OUT)
                    reinterpret_cast<float*>(ga.C[z])[(size_t)row * N + col] = v;
                else
                    reinterpret_cast<unsigned short*>(ga.C[z])[(size_t)row * N + col] = f2bf(v);
            }
        }
}

// ---------------- sum of V over keys, per (b,h,d) — vectorized ----------------
__global__ __launch_bounds__(256) void sumv_kernel(const unsigned short* __restrict__ Vb,
                                                   float* __restrict__ sumV) {
    __shared__ float r[32][HDIM];
    const int bh = blockIdx.x;
    const int b = bh / NHEADS, h = bh % NHEADS;
    const int dg = (threadIdx.x & 7) * 8;
    const int r0 = threadIdx.x >> 3;
    float acc[8] = {};
    const unsigned short* vp = Vb + (size_t)(b * SEQ) * EMBED + h * HDIM + dg;
    for (int j = r0; j < SEQ; j += 32) {
        short8 v = *reinterpret_cast<const short8*>(vp + (size_t)j * EMBED);
#pragma unroll
        for (int e = 0; e < 8; ++e)
            acc[e] += bf2f(((const unsigned short*)&v)[e]);
    }
#pragma unroll
    for (int e = 0; e < 8; ++e) r[r0][dg + e] = acc[e];
    __syncthreads();
    if (threadIdx.x < HDIM) {
        float s = 0.f;
#pragma unroll
        for (int i = 0; i < 32; ++i) s += r[i][threadIdx.x];
        sumV[bh * HDIM + threadIdx.x] = s;
    }
}

// ---------------- MFMA-tile attention: 32 q-rows per block ----------------
__global__ __launch_bounds__(256, 3) void attn_mfma(
    const unsigned short* __restrict__ Q,
    const unsigned short* __restrict__ Kb,
    const unsigned short* __restrict__ Vb,
    const unsigned char* __restrict__ kpm,
    const float* __restrict__ sumV,
    float* __restrict__ attn_out,
    unsigned short* __restrict__ ctx) {
    const int qt = blockIdx.x;
    const int bh = blockIdx.y;
    const int h = bh % NHEADS;
    const int b = bh / NHEADS;
    const int q0 = qt * QT;
    const int kstart = max(q0 - WIN, 0);

    __shared__ float Sf[QT][SPAD];            // scores, then probs (f32)
    __shared__ unsigned short Pb[QT][KPAD];   // probs bf16
    __shared__ unsigned short Vt[HDIM][KPAD]; // V transposed

    const int tid = threadIdx.x;
    const int l = tid & 63;
    const int w = tid >> 6;
    const int fr = l & 15;
    const int ksl = (l >> 4) * 8;

    const size_t base = (size_t)(b * SEQ) * EMBED + h * HDIM;

    // ======== Phase A: scores via MFMA + Vt staging ========
    {
        const int mf = w >> 1;
        const int nt0 = (w & 1) * 5;

        const unsigned short* qrow = Q + base + (size_t)(q0 + mf * 16 + fr) * EMBED;
        short8 aq0 = *reinterpret_cast<const short8*>(qrow + ksl);
        short8 aq1 = *reinterpret_cast<const short8*>(qrow + 32 + ksl);

        f32x4 sacc[5] = {};
#pragma unroll
        for (int t = 0; t < 5; ++t) {
            int jg = kstart + (nt0 + t) * 16 + fr;
            int jc = min(jg, SEQ - 1);
            const unsigned short* krow = Kb + base + (size_t)jc * EMBED;
            short8 b0 = *reinterpret_cast<const short8*>(krow + ksl);
            short8 b1 = *reinterpret_cast<const short8*>(krow + 32 + ksl);
            sacc[t] = __builtin_amdgcn_mfma_f32_16x16x32_bf16(aq0, b0, sacc[t], 0, 0, 0);
            sacc[t] = __builtin_amdgcn_mfma_f32_16x16x32_bf16(aq1, b1, sacc[t], 0, 0, 0);
        }

#pragma unroll
        for (int t = 0; t < 5; ++t) {
            int col = (nt0 + t) * 16 + fr;
            int jg = kstart + col;
            bool jvalid = (jg < SEQ);
            bool mk = jvalid && kpm[b * SEQ + jg];
#pragma unroll
            for (int r = 0; r < 4; ++r) {
                int rowl = mf * 16 + (l >> 4) * 4 + r;
                int qi = q0 + rowl;
                float s = sacc[t][r] * 0.125f;
                if (mk) s = -10000.f;
                int dd = qi - jg;
                if (!jvalid || dd > WIN || dd < -WIN) s = -1e30f;
                Sf[rowl][col] = s;
            }
        }

        // Vt staging (vectorized): 5 passes, 16B global loads, transposed LDS writes
#pragma unroll
        for (int pass = 0; pass < 5; ++pass) {
            int jrel = pass * 32 + (tid >> 3);
            int jg = kstart + jrel;
            int dg = (tid & 7) * 8;
            short8 v = {};
            if (jg < SEQ)
                v = *reinterpret_cast<const short8*>(Vb + base + (size_t)jg * EMBED + dg);
#pragma unroll
            for (int e = 0; e < 8; ++e)
                Vt[dg + e][jrel] = ((const unsigned short*)&v)[e];
        }
    }
    __syncthreads();

    // ======== Phase B: row softmax (8 threads per row) ========
    {
        const int row = tid >> 3;
        const int cg = tid & 7;
        float e[KP / 8];
        float m = -1e30f;
#pragma unroll
        for (int i = 0; i < KP / 8; ++i) {
            float s = Sf[row][cg + i * 8];
            e[i] = s;
            m = fmaxf(m, s);
        }
#pragma unroll
        for (int off = 1; off < 8; off <<= 1) m = fmaxf(m, __shfl_xor(m, off));
        float sum = 0.f;
#pragma unroll
        for (int i = 0; i < KP / 8; ++i) {
            e[i] = __expf(e[i] - m);
            sum += e[i];
        }
#pragma unroll
        for (int off = 1; off < 8; off <<= 1) sum += __shfl_xor(sum, off);
        float inv = 1.f / sum;
#pragma unroll
        for (int i = 0; i < KP / 8; ++i) {
            float p = e[i] * inv;
            int col = cg + i * 8;
            Sf[row][col] = p;
            Pb[row][col] = f2bf(p);
        }
    }
    __syncthreads();

    // ======== Phase D (early): stream full attn rows (NT stores) ========
    {
#pragma unroll
        for (int rr = 0; rr < QT / 4; ++rr) {
            int row = w * (QT / 4) + rr;
            int qi = q0 + row;
            int blo = max(qi - WIN, 0);
            int bhi = min(qi + WIN, SEQ - 1);
            float* __restrict__ orow = attn_out + ((size_t)bh * SEQ + qi) * SEQ;
#pragma unroll
            for (int seg = 0; seg < SEQ / 256; ++seg) {
                int c0 = seg * 256 + l * 4;
                f32x4 v = {1e-6f, 1e-6f, 1e-6f, 1e-6f};
                if (c0 + 3 >= blo && c0 <= bhi) {
#pragma unroll
                    for (int e = 0; e < 4; ++e) {
                        int c = c0 + e;
                        if (c >= blo && c <= bhi) v[e] = Sf[row][c - kstart] + 1e-6f;
                    }
                }
                __builtin_nontemporal_store(v, reinterpret_cast<f32x4*>(orow + c0));
            }
        }
    }

    // ======== Phase C: PV via MFMA -> ctx ========
    {
        const int mf = w >> 1;
        const int nfb = (w & 1) * 2;
        f32x4 oacc[2] = {};
#pragma unroll
        for (int kk = 0; kk < KP / 32; ++kk) {
            short8 a = *reinterpret_cast<const short8*>(&Pb[mf * 16 + fr][kk * 32 + ksl]);
#pragma unroll
            for (int n2 = 0; n2 < 2; ++n2) {
                short8 bv = *reinterpret_cast<const short8*>(&Vt[(nfb + n2) * 16 + fr][kk * 32 + ksl]);
                oacc[n2] = __builtin_amdgcn_mfma_f32_16x16x32_bf16(a, bv, oacc[n2], 0, 0, 0);
            }
        }
#pragma unroll
        for (int n2 = 0; n2 < 2; ++n2) {
            int d = (nfb + n2) * 16 + fr;
            float sv = 1e-6f * sumV[bh * HDIM + d];
#pragma unroll
            for (int r = 0; r < 4; ++r) {
                int rowl = mf * 16 + (l >> 4) * 4 + r;
                ctx[base + (size_t)(q0 + rowl) * EMBED + d] = f2bf(oacc[n2][r] + sv);
            }
        }
    }
}

// ---------------- host ----------------
extern "C" void kernel_launch(void* const* d_in, const int* in_sizes, int n_in,
                              void* d_out, int out_size, void* d_ws, size_t ws_size,
                              hipStream_t stream) {
    const float* q_in = (const float*)d_in[0];
    const float* k_in = (const float*)d_in[1];
    const float* v_in = (const float*)d_in[2];
    const unsigned char* kpm = (const unsigned char*)d_in[3];
    const float* Wq = (const float*)d_in[4];
    const float* bq = (const float*)d_in[5];
    const float* Wk = (const float*)d_in[6];
    const float* bk = (const float*)d_in[7];
    const float* Wv = (const float*)d_in[8];
    const float* bv = (const float*)d_in[9];
    const float* Wo = (const float*)d_in[10];
    const float* bo = (const float*)d_in[11];

    char* ws = (char*)d_ws;
    size_t off = 0;
    auto alloc = [&](size_t bytes) {
        void* p = ws + off;
        off += (bytes + 255) & ~255ULL;
        return p;
    };
    const size_t XB = (size_t)MROWS * EMBED * 2;
    const size_t WB = (size_t)EMBED * EMBED * 2;
    unsigned short* xq = (unsigned short*)alloc(XB);
    unsigned short* xk = (unsigned short*)alloc(XB);
    unsigned short* xv = (unsigned short*)alloc(XB);
    unsigned short* wqb = (unsigned short*)alloc(WB);
    unsigned short* wkb = (unsigned short*)alloc(WB);
    unsigned short* wvb = (unsigned short*)alloc(WB);
    unsigned short* wob = (unsigned short*)alloc(WB);
    unsigned short* Qb = (unsigned short*)alloc(XB);
    unsigned short* Kb = (unsigned short*)alloc(XB);
    unsigned short* Vb = (unsigned short*)alloc(XB);
    unsigned short* ctx = (unsigned short*)alloc(XB);
    float* sumV = (float*)alloc((size_t)NBH * HDIM * 4);

    float* out0 = (float*)d_out;
    float* attn_out = out0 + (size_t)MROWS * EMBED;

    // ---- one fused conversion launch ----
    {
        CvtArgs ca;
        const float* srcs[7] = {q_in, k_in, v_in, Wq, Wk, Wv, Wo};
        unsigned short* dsts[7] = {xq, xk, xv, wqb, wkb, wvb, wob};
        int bacc = 0;
        for (int s = 0; s < 7; ++s) {
            ca.src[s] = srcs[s];
            ca.dst[s] = dsts[s];
            ca.n4[s] = (s < 3) ? (MROWS * EMBED / 4) : (EMBED * EMBED / 4);
            ca.bstart[s] = bacc;
            bacc += (ca.n4[s] + 255) / 256;
        }
        ca.bstart[7] = bacc;
        cvt_all<<<dim3(bacc), dim3(256), 0, stream>>>(ca);
    }

    // QKV projections
    {
        GArgs ga;
        ga.A[0] = xq;  ga.A[1] = xk;  ga.A[2] = xv;
        ga.Bm[0] = wqb; ga.Bm[1] = wkb; ga.Bm[2] = wvb;
        ga.bias[0] = bq; ga.bias[1] = bk; ga.bias[2] = bv;
        ga.C[0] = Qb; ga.C[1] = Kb; ga.C[2] = Vb;
        gemm_nt<0><<<dim3(EMBED / 128, MROWS / 128, 3), dim3(256), 0, stream>>>(
            ga, MROWS, EMBED, EMBED);
    }

    sumv_kernel<<<dim3(NBH), dim3(256), 0, stream>>>(Vb, sumV);

    attn_mfma<<<dim3(SEQ / QT, NBH), dim3(256), 0, stream>>>(
        Qb, Kb, Vb, kpm, sumV, attn_out, ctx);

    // output projection -> fp32 out
    {
        GArgs ga;
        ga.A[0] = ctx;  ga.A[1] = ctx;  ga.A[2] = ctx;
        ga.Bm[0] = wob; ga.Bm[1] = wob; ga.Bm[2] = wob;
        ga.bias[0] = bo; ga.bias[1] = bo; ga.bias[2] = bo;
        ga.C[0] = out0; ga.C[1] = out0; ga.C[2] = out0;
        gemm_nt<1><<<dim3(EMBED / 128, MROWS / 128, 1), dim3(256), 0, stream>>>(
            ga, MROWS, EMBED, EMBED);
    }
}